// Round 16
// baseline (150.904 us; speedup 1.0000x reference)
//
#include <hip/hip_runtime.h>
#include <math.h>

#define D_DIM 128
#define M_CLUSTERS 64
#define BLOCK 256
#define GRIDB 1024
#define W_TOTAL 4096     // resident waves: 1024 blocks x 4 waves = 4/SIMD

typedef __bf16 bf16x8 __attribute__((ext_vector_type(8)));
typedef float f32x4 __attribute__((ext_vector_type(4)));

union B8 { int4 i; bf16x8 b; };
union F4 { float4 v; float f[4]; };

__device__ __forceinline__ float zval(float sq) {
    float dd = sqrtf(fmaxf(sq, 0.0f));
    float sg = __fdividef(1.0f, 1.0f + __expf(dd));
    return -__logf(sg + 1e-8f);
}

// Single fused kernel: per-block mus->bf16 LDS prep + m2, 4-stage X/r stream
// (r11-verified body), per-wave partials, last-block deterministic reduce.
__global__ __launch_bounds__(BLOCK, 4) void iso_main(
        const float* __restrict__ X, const float* __restrict__ r,
        const float4* __restrict__ mus4, float* __restrict__ partials,
        unsigned int* __restrict__ cnt, float* __restrict__ out,
        int N, float invN) {
    __shared__ __align__(16) char bs[16384 + 256];  // B bf16 swizzled | m2[64]
    __shared__ float wsum[4];
    __shared__ unsigned int isLast;

    const int tid = threadIdx.x;
    const int lane = tid & 63;
    const int la = lane & 15;
    const int lg = lane >> 4;
    const int gid = blockIdx.x * 4 + (tid >> 6);
    const int ntiles = N >> 4;                 // 12500 (16 | N)

    // ---- Issue X(tile gid) early so it flies under the prep work ----
    float4 xA[8], xB[8];
    {
        const char* xb = (const char*)X + (size_t)gid * 8192 +
                         (size_t)la * 512 + lg * 32;
        xA[0] = *(const float4*)(xb + 0);   xA[1] = *(const float4*)(xb + 16);
        xA[2] = *(const float4*)(xb + 128); xA[3] = *(const float4*)(xb + 144);
        xA[4] = *(const float4*)(xb + 256); xA[5] = *(const float4*)(xb + 272);
        xA[6] = *(const float4*)(xb + 384); xA[7] = *(const float4*)(xb + 400);
    }

    // ---- Per-block prep: mus f32 (L2-hot) -> bf16 LDS (r6 swizzle) + m2 ----
    // Thread t owns chunks f=t*4..t*4+3 (all in cluster c=t>>2, slots t*4&15..).
    {
        float msq = 0.f;
#pragma unroll
        for (int i = 0; i < 4; ++i) {
            int f = tid * 4 + i;
            int c = f >> 4, sl = f & 15;
            float4 v0 = mus4[f * 2 + 0];
            float4 v1 = mus4[f * 2 + 1];
            B8 p;
            p.b[0] = (__bf16)v0.x; p.b[1] = (__bf16)v0.y;
            p.b[2] = (__bf16)v0.z; p.b[3] = (__bf16)v0.w;
            p.b[4] = (__bf16)v1.x; p.b[5] = (__bf16)v1.y;
            p.b[6] = (__bf16)v1.z; p.b[7] = (__bf16)v1.w;
            *(int4*)(bs + c * 256 + ((sl ^ (c & 7)) * 16)) = p.i;
            msq = fmaf(v0.x, v0.x, msq); msq = fmaf(v0.y, v0.y, msq);
            msq = fmaf(v0.z, v0.z, msq); msq = fmaf(v0.w, v0.w, msq);
            msq = fmaf(v1.x, v1.x, msq); msq = fmaf(v1.y, v1.y, msq);
            msq = fmaf(v1.z, v1.z, msq); msq = fmaf(v1.w, v1.w, msq);
        }
        // 4 threads per cluster -> pairwise shuffle reduce (f32, exact order).
        msq += __shfl_xor(msq, 1, 64);
        msq += __shfl_xor(msq, 2, 64);
        if ((tid & 3) == 0)
            ((float*)(bs + 16384))[tid >> 2] = msq;
    }
    __syncthreads();

    F4 m2r[4];
    {
        const float4* m2p = (const float4*)(bs + 16384);
#pragma unroll
        for (int cb = 0; cb < 4; ++cb) m2r[cb].v = m2p[cb * 4 + lg];
    }

    float partial = 0.f;

    // One pipeline stage (r11-verified body): consume cur, prefetch into nxt.
    auto run_stage = [&](int k, bool pf, const float4 (&cur)[8], float4 (&nxt)[8]) {
        const int tk = gid + k * W_TOTAL;
        const bool valid = tk < ntiles;            // wave-uniform
        const size_t ta = valid ? (size_t)tk : (size_t)gid;

        // r loads for this tile (used ~600cy later in the epilogue).
        F4 rv[4];
        const char* rb = (const char*)r + ta * 4096 + (size_t)la * 256 + lg * 16;
        rv[0].v = *(const float4*)(rb + 0);
        rv[1].v = *(const float4*)(rb + 64);
        rv[2].v = *(const float4*)(rb + 128);
        rv[3].v = *(const float4*)(rb + 192);

        // Prefetch X(t+1) (predicated: no phantom over-fetch; garbage-but-
        // finite stale regs in the skipped case are discarded via `valid`).
        if (pf) {
            int tn = gid + (k + 1) * W_TOTAL;
            if (tn < ntiles) {
                const char* xb = (const char*)X + (size_t)tn * 8192 +
                                 (size_t)la * 512 + lg * 32;
                nxt[0] = *(const float4*)(xb + 0);
                nxt[1] = *(const float4*)(xb + 16);
                nxt[2] = *(const float4*)(xb + 128);
                nxt[3] = *(const float4*)(xb + 144);
                nxt[4] = *(const float4*)(xb + 256);
                nxt[5] = *(const float4*)(xb + 272);
                nxt[6] = *(const float4*)(xb + 384);
                nxt[7] = *(const float4*)(xb + 400);
            }
        }
        __builtin_amdgcn_sched_barrier(0);

        // Convert cur -> bf16 fragments + exact f32 x2.
        B8 xf[4];
        float x2 = 0.f;
#pragma unroll
        for (int kk = 0; kk < 4; ++kk) {
            float4 a = cur[2 * kk], b = cur[2 * kk + 1];
            xf[kk].b[0] = (__bf16)a.x; xf[kk].b[1] = (__bf16)a.y;
            xf[kk].b[2] = (__bf16)a.z; xf[kk].b[3] = (__bf16)a.w;
            xf[kk].b[4] = (__bf16)b.x; xf[kk].b[5] = (__bf16)b.y;
            xf[kk].b[6] = (__bf16)b.z; xf[kk].b[7] = (__bf16)b.w;
            x2 = fmaf(a.x, a.x, x2); x2 = fmaf(a.y, a.y, x2);
            x2 = fmaf(a.z, a.z, x2); x2 = fmaf(a.w, a.w, x2);
            x2 = fmaf(b.x, b.x, x2); x2 = fmaf(b.y, b.y, x2);
            x2 = fmaf(b.z, b.z, x2); x2 = fmaf(b.w, b.w, x2);
        }

        // MFMA: A = mu frags from LDS (swizzle-matched), B = x frags.
        f32x4 acc[4];
#pragma unroll
        for (int cb = 0; cb < 4; ++cb)
#pragma unroll
            for (int q = 0; q < 4; ++q) acc[cb][q] = 0.f;
#pragma unroll
        for (int kk = 0; kk < 4; ++kk)
#pragma unroll
            for (int cb = 0; cb < 4; ++cb) {
                int c = cb * 16 + la;
                B8 bfr;
                bfr.i = *(const int4*)(bs + c * 256 +
                                       (((kk * 4 + lg) ^ (c & 7)) * 16));
                acc[cb] = __builtin_amdgcn_mfma_f32_16x16x32_bf16(
                    bfr.b, xf[kk].b, acc[cb], 0, 0, 0);
            }

        // x2 quarter-sums at (la,lg) -> reduce over lg; lane keeps row la's x2.
        x2 += __shfl_xor(x2, 16, 64);
        x2 += __shfl_xor(x2, 32, 64);

        // Epilogue: acc[cb][q] = dot(mu[cb*16+lg*4+q], x[row la]).
        float p = 0.f;
#pragma unroll
        for (int cb = 0; cb < 4; ++cb)
#pragma unroll
            for (int q = 0; q < 4; ++q) {
                float sq = x2 + m2r[cb].f[q] - 2.0f * acc[cb][q];
                p = fmaf(rv[cb].f[q], zval(sq), p);
            }
        if (valid) partial += p;
    };

    run_stage(0, true, xA, xB);
    run_stage(1, true, xB, xA);
    run_stage(2, true, xA, xB);
    run_stage(3, false, xB, xA);

    // Wave reduce: 64 lanes = 16 rows x 4 cluster-blocks per tile.
#pragma unroll
    for (int off = 32; off > 0; off >>= 1)
        partial += __shfl_down(partial, off, 64);
    if (lane == 0) partials[gid] = partial;

    // ---- Last-block deterministic grid reduction ----
    __threadfence();            // flush partials to device scope
    __syncthreads();            // all 4 waves' stores+fences done
    if (tid == 0) {
        unsigned int old = atomicAdd(cnt, 1u);
        isLast = (old == GRIDB - 1) ? 1u : 0u;
    }
    __syncthreads();
    if (isLast) {
        __threadfence();        // acquire side: see all blocks' partials
        float s = 0.f;
        for (int i = tid; i < W_TOTAL; i += BLOCK) s += partials[i];  // fixed order
#pragma unroll
        for (int off = 32; off > 0; off >>= 1)
            s += __shfl_down(s, off, 64);
        if (lane == 0) wsum[tid >> 6] = s;
        __syncthreads();
        if (tid == 0) {
            out[0] = (wsum[0] + wsum[1] + wsum[2] + wsum[3]) * invN;
            *cnt = 0;           // belt-and-suspenders (memset also resets)
        }
    }
}

extern "C" void kernel_launch(void* const* d_in, const int* in_sizes, int n_in,
                              void* d_out, int out_size, void* d_ws, size_t ws_size,
                              hipStream_t stream) {
    const float* X = (const float*)d_in[0];    // [N,128]
    const float* r = (const float*)d_in[1];    // [N,64]
    const float* mus = (const float*)d_in[2];  // [64,128]
    const int N = in_sizes[0] / D_DIM;

    // ws: partials (4096 f32 = 16KB) | cnt (u32)
    float* partials = (float*)d_ws;
    unsigned int* cnt = (unsigned int*)((char*)d_ws + W_TOTAL * sizeof(float));

    hipMemsetAsync(cnt, 0, sizeof(unsigned int), stream);
    hipLaunchKernelGGL(iso_main, dim3(GRIDB), dim3(BLOCK), 0, stream,
                       X, r, (const float4*)mus, partials, cnt, (float*)d_out,
                       N, 1.0f / (float)N);
}

// Round 17
// 150.743 us; speedup vs baseline: 1.0011x; 1.0011x over previous
//
#include <hip/hip_runtime.h>
#include <math.h>

#define D_DIM 128
#define M_CLUSTERS 64
#define BLOCK 256
#define GRIDB 1024
#define W_TOTAL 4096     // resident waves: 1024 blocks x 4 waves = 4/SIMD

typedef __bf16 bf16x8 __attribute__((ext_vector_type(8)));
typedef float f32x4 __attribute__((ext_vector_type(4)));

union B8 { int4 i; bf16x8 b; };
union F4 { float4 v; float f[4]; };

__device__ __forceinline__ float zval(float sq) {
    float dd = sqrtf(fmaxf(sq, 0.0f));
    float sg = __fdividef(1.0f, 1.0f + __expf(dd));
    return -__logf(sg + 1e-8f);
}

// Single fused kernel: per-block mus->bf16 LDS prep + m2, 4-stage X/r stream
// (r11-verified body), per-wave partials, last-block deterministic reduce.
__global__ __launch_bounds__(BLOCK, 4) void iso_main(
        const float* __restrict__ X, const float* __restrict__ r,
        const float4* __restrict__ mus4, float* __restrict__ partials,
        unsigned int* __restrict__ cnt, float* __restrict__ out,
        int N, float invN) {
    __shared__ __align__(16) char bs[16384 + 256];  // B bf16 swizzled | m2[64]
    __shared__ float wsum[4];
    __shared__ unsigned int isLast;

    const int tid = threadIdx.x;
    const int lane = tid & 63;
    const int la = lane & 15;
    const int lg = lane >> 4;
    const int gid = blockIdx.x * 4 + (tid >> 6);
    const int ntiles = N >> 4;                 // 12500 (16 | N)

    // ---- Issue X(tile gid) early so it flies under the prep work ----
    float4 xA[8], xB[8];
    {
        const char* xb = (const char*)X + (size_t)gid * 8192 +
                         (size_t)la * 512 + lg * 32;
        xA[0] = *(const float4*)(xb + 0);   xA[1] = *(const float4*)(xb + 16);
        xA[2] = *(const float4*)(xb + 128); xA[3] = *(const float4*)(xb + 144);
        xA[4] = *(const float4*)(xb + 256); xA[5] = *(const float4*)(xb + 272);
        xA[6] = *(const float4*)(xb + 384); xA[7] = *(const float4*)(xb + 400);
    }

    // ---- Per-block prep: mus f32 (L2-hot) -> bf16 LDS (r6 swizzle) + m2 ----
    // Thread t owns chunks f=t*4..t*4+3 (all in cluster c=t>>2, slots t*4&15..).
    {
        float msq = 0.f;
#pragma unroll
        for (int i = 0; i < 4; ++i) {
            int f = tid * 4 + i;
            int c = f >> 4, sl = f & 15;
            float4 v0 = mus4[f * 2 + 0];
            float4 v1 = mus4[f * 2 + 1];
            B8 p;
            p.b[0] = (__bf16)v0.x; p.b[1] = (__bf16)v0.y;
            p.b[2] = (__bf16)v0.z; p.b[3] = (__bf16)v0.w;
            p.b[4] = (__bf16)v1.x; p.b[5] = (__bf16)v1.y;
            p.b[6] = (__bf16)v1.z; p.b[7] = (__bf16)v1.w;
            *(int4*)(bs + c * 256 + ((sl ^ (c & 7)) * 16)) = p.i;
            msq = fmaf(v0.x, v0.x, msq); msq = fmaf(v0.y, v0.y, msq);
            msq = fmaf(v0.z, v0.z, msq); msq = fmaf(v0.w, v0.w, msq);
            msq = fmaf(v1.x, v1.x, msq); msq = fmaf(v1.y, v1.y, msq);
            msq = fmaf(v1.z, v1.z, msq); msq = fmaf(v1.w, v1.w, msq);
        }
        // 4 threads per cluster -> pairwise shuffle reduce (f32, exact order).
        msq += __shfl_xor(msq, 1, 64);
        msq += __shfl_xor(msq, 2, 64);
        if ((tid & 3) == 0)
            ((float*)(bs + 16384))[tid >> 2] = msq;
    }
    __syncthreads();

    F4 m2r[4];
    {
        const float4* m2p = (const float4*)(bs + 16384);
#pragma unroll
        for (int cb = 0; cb < 4; ++cb) m2r[cb].v = m2p[cb * 4 + lg];
    }

    float partial = 0.f;

    // One pipeline stage (r11-verified body): consume cur, prefetch into nxt.
    auto run_stage = [&](int k, bool pf, const float4 (&cur)[8], float4 (&nxt)[8]) {
        const int tk = gid + k * W_TOTAL;
        const bool valid = tk < ntiles;            // wave-uniform
        const size_t ta = valid ? (size_t)tk : (size_t)gid;

        // r loads for this tile (used ~600cy later in the epilogue).
        F4 rv[4];
        const char* rb = (const char*)r + ta * 4096 + (size_t)la * 256 + lg * 16;
        rv[0].v = *(const float4*)(rb + 0);
        rv[1].v = *(const float4*)(rb + 64);
        rv[2].v = *(const float4*)(rb + 128);
        rv[3].v = *(const float4*)(rb + 192);

        // Prefetch X(t+1) (predicated: no phantom over-fetch; garbage-but-
        // finite stale regs in the skipped case are discarded via `valid`).
        if (pf) {
            int tn = gid + (k + 1) * W_TOTAL;
            if (tn < ntiles) {
                const char* xb = (const char*)X + (size_t)tn * 8192 +
                                 (size_t)la * 512 + lg * 32;
                nxt[0] = *(const float4*)(xb + 0);
                nxt[1] = *(const float4*)(xb + 16);
                nxt[2] = *(const float4*)(xb + 128);
                nxt[3] = *(const float4*)(xb + 144);
                nxt[4] = *(const float4*)(xb + 256);
                nxt[5] = *(const float4*)(xb + 272);
                nxt[6] = *(const float4*)(xb + 384);
                nxt[7] = *(const float4*)(xb + 400);
            }
        }
        __builtin_amdgcn_sched_barrier(0);

        // Convert cur -> bf16 fragments + exact f32 x2.
        B8 xf[4];
        float x2 = 0.f;
#pragma unroll
        for (int kk = 0; kk < 4; ++kk) {
            float4 a = cur[2 * kk], b = cur[2 * kk + 1];
            xf[kk].b[0] = (__bf16)a.x; xf[kk].b[1] = (__bf16)a.y;
            xf[kk].b[2] = (__bf16)a.z; xf[kk].b[3] = (__bf16)a.w;
            xf[kk].b[4] = (__bf16)b.x; xf[kk].b[5] = (__bf16)b.y;
            xf[kk].b[6] = (__bf16)b.z; xf[kk].b[7] = (__bf16)b.w;
            x2 = fmaf(a.x, a.x, x2); x2 = fmaf(a.y, a.y, x2);
            x2 = fmaf(a.z, a.z, x2); x2 = fmaf(a.w, a.w, x2);
            x2 = fmaf(b.x, b.x, x2); x2 = fmaf(b.y, b.y, x2);
            x2 = fmaf(b.z, b.z, x2); x2 = fmaf(b.w, b.w, x2);
        }

        // MFMA: A = mu frags from LDS (swizzle-matched), B = x frags.
        f32x4 acc[4];
#pragma unroll
        for (int cb = 0; cb < 4; ++cb)
#pragma unroll
            for (int q = 0; q < 4; ++q) acc[cb][q] = 0.f;
#pragma unroll
        for (int kk = 0; kk < 4; ++kk)
#pragma unroll
            for (int cb = 0; cb < 4; ++cb) {
                int c = cb * 16 + la;
                B8 bfr;
                bfr.i = *(const int4*)(bs + c * 256 +
                                       (((kk * 4 + lg) ^ (c & 7)) * 16));
                acc[cb] = __builtin_amdgcn_mfma_f32_16x16x32_bf16(
                    bfr.b, xf[kk].b, acc[cb], 0, 0, 0);
            }

        // x2 quarter-sums at (la,lg) -> reduce over lg; lane keeps row la's x2.
        x2 += __shfl_xor(x2, 16, 64);
        x2 += __shfl_xor(x2, 32, 64);

        // Epilogue: acc[cb][q] = dot(mu[cb*16+lg*4+q], x[row la]).
        float p = 0.f;
#pragma unroll
        for (int cb = 0; cb < 4; ++cb)
#pragma unroll
            for (int q = 0; q < 4; ++q) {
                float sq = x2 + m2r[cb].f[q] - 2.0f * acc[cb][q];
                p = fmaf(rv[cb].f[q], zval(sq), p);
            }
        if (valid) partial += p;
    };

    run_stage(0, true, xA, xB);
    run_stage(1, true, xB, xA);
    run_stage(2, true, xA, xB);
    run_stage(3, false, xB, xA);

    // Wave reduce: 64 lanes = 16 rows x 4 cluster-blocks per tile.
#pragma unroll
    for (int off = 32; off > 0; off >>= 1)
        partial += __shfl_down(partial, off, 64);
    if (lane == 0) partials[gid] = partial;

    // ---- Last-block deterministic grid reduction ----
    __threadfence();            // flush partials to device scope
    __syncthreads();            // all 4 waves' stores+fences done
    if (tid == 0) {
        unsigned int old = atomicAdd(cnt, 1u);
        isLast = (old == GRIDB - 1) ? 1u : 0u;
    }
    __syncthreads();
    if (isLast) {
        __threadfence();        // acquire side: see all blocks' partials
        float s = 0.f;
        for (int i = tid; i < W_TOTAL; i += BLOCK) s += partials[i];  // fixed order
#pragma unroll
        for (int off = 32; off > 0; off >>= 1)
            s += __shfl_down(s, off, 64);
        if (lane == 0) wsum[tid >> 6] = s;
        __syncthreads();
        if (tid == 0) {
            out[0] = (wsum[0] + wsum[1] + wsum[2] + wsum[3]) * invN;
            *cnt = 0;           // belt-and-suspenders (memset also resets)
        }
    }
}

extern "C" void kernel_launch(void* const* d_in, const int* in_sizes, int n_in,
                              void* d_out, int out_size, void* d_ws, size_t ws_size,
                              hipStream_t stream) {
    const float* X = (const float*)d_in[0];    // [N,128]
    const float* r = (const float*)d_in[1];    // [N,64]
    const float* mus = (const float*)d_in[2];  // [64,128]
    const int N = in_sizes[0] / D_DIM;

    // ws: partials (4096 f32 = 16KB) | cnt (u32)
    float* partials = (float*)d_ws;
    unsigned int* cnt = (unsigned int*)((char*)d_ws + W_TOTAL * sizeof(float));

    hipMemsetAsync(cnt, 0, sizeof(unsigned int), stream);
    hipLaunchKernelGGL(iso_main, dim3(GRIDB), dim3(BLOCK), 0, stream,
                       X, r, (const float4*)mus, partials, cnt, (float*)d_out,
                       N, 1.0f / (float)N);
}

// Round 18
// 45.227 us; speedup vs baseline: 3.3366x; 3.3330x over previous
//
#include <hip/hip_runtime.h>
#include <math.h>

#define D_DIM 128
#define M_CLUSTERS 64
#define BLOCK 512        // 8 waves per block
#define GRIDB 1024       // 4 blocks/CU, all resident
#define W_TOTAL 8192     // 8 waves/SIMD resident at VGPR<=64 (m69 tier)
#define RBLOCK 1024

typedef __bf16 bf16x8 __attribute__((ext_vector_type(8)));
typedef float f32x4 __attribute__((ext_vector_type(4)));

union B8 { int4 i; bf16x8 b; };
union F4 { float4 v; float f[4]; };

__device__ __forceinline__ float zval(float sq) {
    float dd = sqrtf(fmaxf(sq, 0.0f));
    float sg = __fdividef(1.0f, 1.0f + __expf(dd));
    return -__logf(sg + 1e-8f);
}

// Async global->LDS, 16B/lane: lds dest = base + lane*16 (HW rule). r6-proven.
__device__ __forceinline__ void gload16(const void* g, void* l) {
    __builtin_amdgcn_global_load_lds(
        (const __attribute__((address_space(1))) unsigned int*)g,
        (__attribute__((address_space(3))) unsigned int*)l, 16, 0, 0);
}

// Prep (grid=4): muB4 = bf16(mus) [64 clusters][16 slots of 16B]; m2 = ||mu||^2.
__global__ void iso_prep(const float4* __restrict__ mus4, int4* __restrict__ muB4,
                         float* __restrict__ m2) {
    const int f = blockIdx.x * 256 + threadIdx.x;   // 1024 chunks of 8 f32
    float4 v0 = mus4[f * 2 + 0];
    float4 v1 = mus4[f * 2 + 1];
    B8 p;
    p.b[0] = (__bf16)v0.x; p.b[1] = (__bf16)v0.y;
    p.b[2] = (__bf16)v0.z; p.b[3] = (__bf16)v0.w;
    p.b[4] = (__bf16)v1.x; p.b[5] = (__bf16)v1.y;
    p.b[6] = (__bf16)v1.z; p.b[7] = (__bf16)v1.w;
    muB4[f] = p.i;
    if (blockIdx.x == 0 && threadIdx.x < M_CLUSTERS) {
        const float4* mv = mus4 + threadIdx.x * (D_DIM / 4);
        float s = 0.f;
#pragma unroll
        for (int d = 0; d < D_DIM / 4; ++d) {
            float4 v = mv[d];
            s = fmaf(v.x, v.x, s);
            s = fmaf(v.y, v.y, s);
            s = fmaf(v.z, v.z, s);
            s = fmaf(v.w, v.w, s);
        }
        m2[threadIdx.x] = s;
    }
}

// Main: 8192 resident waves (8/SIMD at VGPR<=64), each 1-2 tiles of 16 rows.
// Simple body, TLP does the latency hiding. B + m2 in LDS once per block.
__global__ __launch_bounds__(BLOCK, 8) void iso_main(
        const float* __restrict__ X, const float* __restrict__ r,
        const int4* __restrict__ muB4, const float* __restrict__ m2g,
        float* __restrict__ partials, int N) {
    __shared__ __align__(16) char bs[16384 + 256];   // B (swizzled) | m2[64]

    const int tid = threadIdx.x;
    const int lane = tid & 63;
    const int la = lane & 15;
    const int lg = lane >> 4;
    const int w = tid >> 6;
    const int gid = blockIdx.x * 8 + w;
    const int ntiles = N >> 4;                 // 12500 (16 | N)

    // ---- Prologue: B -> LDS via DMA (r6-verified swizzle), m2 -> LDS ----
#pragma unroll
    for (int i = 0; i < 2; ++i) {
        int kchunk = w * 2 + i;
        int c = kchunk * 4 + (lane >> 4);
        int slot = (lane & 15) ^ (c & 7);
        gload16(muB4 + c * 16 + slot, bs + kchunk * 1024);
    }
    if (tid < M_CLUSTERS) ((float*)(bs + 16384))[tid] = m2g[tid];
    __syncthreads();   // drains DMA; bs/m2 visible

    float partial = 0.f;

    for (int k = 0; k < 2; ++k) {
        const int tk = gid + k * W_TOTAL;
        if (tk >= ntiles) break;               // wave-uniform

        // X: lane (la,lg) holds row tk*16+la, k-chunks lg*8 per 32-wide kk.
        const char* xb = (const char*)X + (size_t)tk * 8192 +
                         (size_t)la * 512 + lg * 32;
        float4 xv[8];
        xv[0] = *(const float4*)(xb + 0);   xv[1] = *(const float4*)(xb + 16);
        xv[2] = *(const float4*)(xb + 128); xv[3] = *(const float4*)(xb + 144);
        xv[4] = *(const float4*)(xb + 256); xv[5] = *(const float4*)(xb + 272);
        xv[6] = *(const float4*)(xb + 384); xv[7] = *(const float4*)(xb + 400);

        // r: lane needs r[row=tk*16+la][lg*16 + cb*... ] per epilogue layout.
        F4 rv[4];
        const char* rb = (const char*)r + (size_t)tk * 4096 +
                         (size_t)la * 256 + lg * 16;
        rv[0].v = *(const float4*)(rb + 0);
        rv[1].v = *(const float4*)(rb + 64);
        rv[2].v = *(const float4*)(rb + 128);
        rv[3].v = *(const float4*)(rb + 192);

        // Convert -> bf16 fragments + exact f32 x2 (xv dies here).
        B8 xf[4];
        float x2 = 0.f;
#pragma unroll
        for (int kk = 0; kk < 4; ++kk) {
            float4 a = xv[2 * kk], b = xv[2 * kk + 1];
            xf[kk].b[0] = (__bf16)a.x; xf[kk].b[1] = (__bf16)a.y;
            xf[kk].b[2] = (__bf16)a.z; xf[kk].b[3] = (__bf16)a.w;
            xf[kk].b[4] = (__bf16)b.x; xf[kk].b[5] = (__bf16)b.y;
            xf[kk].b[6] = (__bf16)b.z; xf[kk].b[7] = (__bf16)b.w;
            x2 = fmaf(a.x, a.x, x2); x2 = fmaf(a.y, a.y, x2);
            x2 = fmaf(a.z, a.z, x2); x2 = fmaf(a.w, a.w, x2);
            x2 = fmaf(b.x, b.x, x2); x2 = fmaf(b.y, b.y, x2);
            x2 = fmaf(b.z, b.z, x2); x2 = fmaf(b.w, b.w, x2);
        }

        // MFMA: A = mu frags from LDS (swizzle-matched read), B = x frags.
        f32x4 acc[4];
#pragma unroll
        for (int cb = 0; cb < 4; ++cb)
#pragma unroll
            for (int q = 0; q < 4; ++q) acc[cb][q] = 0.f;
#pragma unroll
        for (int kk = 0; kk < 4; ++kk)
#pragma unroll
            for (int cb = 0; cb < 4; ++cb) {
                int c = cb * 16 + la;
                B8 bfr;
                bfr.i = *(const int4*)(bs + c * 256 +
                                       (((kk * 4 + lg) ^ (c & 7)) * 16));
                acc[cb] = __builtin_amdgcn_mfma_f32_16x16x32_bf16(
                    bfr.b, xf[kk].b, acc[cb], 0, 0, 0);
            }

        // x2 quarter-sums at (la,lg) -> reduce over lg; lane keeps row la's x2.
        x2 += __shfl_xor(x2, 16, 64);
        x2 += __shfl_xor(x2, 32, 64);

        // m2 from LDS (address depends only on lg -> broadcast, conflict-free).
        F4 m2r[4];
        const float4* m2p = (const float4*)(bs + 16384);
#pragma unroll
        for (int cb = 0; cb < 4; ++cb) m2r[cb].v = m2p[cb * 4 + lg];

        // Epilogue: acc[cb][q] = dot(mu[cb*16+lg*4+q], x[row la]) (r9-proven).
#pragma unroll
        for (int cb = 0; cb < 4; ++cb)
#pragma unroll
            for (int q = 0; q < 4; ++q) {
                float sq = x2 + m2r[cb].f[q] - 2.0f * acc[cb][q];
                partial = fmaf(rv[cb].f[q], zval(sq), partial);
            }
    }

    // Wave reduce: 64 lanes = 16 rows x 4 cluster-blocks per tile.
#pragma unroll
    for (int off = 32; off > 0; off >>= 1)
        partial += __shfl_down(partial, off, 64);
    if (lane == 0) partials[gid] = partial;
}

// Deterministic fixed-order final reduction over 8192 per-wave partials.
__global__ __launch_bounds__(RBLOCK) void iso_reduce(
        const float* __restrict__ partials, int n,
        float* __restrict__ out, float invN) {
    float s = 0.f;
    for (int i = threadIdx.x; i < n; i += RBLOCK) s += partials[i];
#pragma unroll
    for (int off = 32; off > 0; off >>= 1)
        s += __shfl_down(s, off, 64);
    __shared__ float wsum[RBLOCK / 64];
    const int lane = threadIdx.x & 63;
    const int wid = threadIdx.x >> 6;
    if (lane == 0) wsum[wid] = s;
    __syncthreads();
    if (threadIdx.x == 0) {
        float t = 0.f;
#pragma unroll
        for (int j = 0; j < RBLOCK / 64; ++j) t += wsum[j];
        out[0] = t * invN;
    }
}

extern "C" void kernel_launch(void* const* d_in, const int* in_sizes, int n_in,
                              void* d_out, int out_size, void* d_ws, size_t ws_size,
                              hipStream_t stream) {
    const float* X = (const float*)d_in[0];    // [N,128]
    const float* r = (const float*)d_in[1];    // [N,64]
    const float* mus = (const float*)d_in[2];  // [64,128]
    const int N = in_sizes[0] / D_DIM;

    // ws: muB4 (1024 int4 = 16KB) | m2 (64 f32) | partials (W_TOTAL f32)
    int4* muB4 = (int4*)d_ws;
    float* m2 = (float*)((char*)d_ws + 16384);
    float* partials = m2 + M_CLUSTERS;

    hipLaunchKernelGGL(iso_prep, dim3(4), dim3(256), 0, stream,
                       (const float4*)mus, muB4, m2);
    hipLaunchKernelGGL(iso_main, dim3(GRIDB), dim3(BLOCK), 0, stream,
                       X, r, muB4, m2, partials, N);
    hipLaunchKernelGGL(iso_reduce, dim3(1), dim3(RBLOCK), 0, stream,
                       partials, W_TOTAL, (float*)d_out, 1.0f / (float)N);
}